// Round 3
// baseline (13156.033 us; speedup 1.0000x reference)
//
#include <hip/hip_runtime.h>
#include <math.h>

// Deep ESN, fp32, persistent wavefront-pipelined kernel, round 3.
// Changes vs R2: state loads are plain cached float4 (L2-shared across the
// XCD's blocks) instead of sc1 atomic loads (which bypassed L1+L2 and paid
// ~900cyc fabric latency per load, no dedupe). Visibility: stores remain
// relaxed AGENT-scope (write-through), barrier arrive is RELEASE, poll is
// RELAXED (no per-poll invalidate), and ONE agent acquire fence per block
// per tick (single buffer_inv) replaces R2's cache-bypassing loads.

#define TT    512
#define RDIM  1024
#define EDIM  256
#define NL    4
#define BB    32
#define NBLK  512          // 128 blocks per layer
#define JW    8            // output columns per block
#define HDIM  (RDIM * NL)  // 4096
#define NPAN  4            // 4 panels of 8 batch rows
#define CSTRIDE 32         // dwords between barrier counters (128B lines)

#define S_ELEMS   (2 * NL * NPAN * RDIM * 8)   // 262144 floats, 1MB
#define FIN_ELEMS (BB * HDIM)

typedef unsigned long long ull;

__device__ __forceinline__ ull pack2(float a, float b) {
    union { float f[2]; ull u; } c; c.f[0] = a; c.f[1] = b; return c.u;
}

// ---------------------------------------------------------------- gather ----
// xe[t][panel][k][8b] : panel layout matching reservoir reads
__global__ void gather_kernel(const int* __restrict__ x,
                              const float* __restrict__ embed,
                              float* __restrict__ xe)
{
    __shared__ int   ids[BB];
    __shared__ float sh[BB * (EDIM + 1)];
    const int t = blockIdx.x, tid = threadIdx.x;
    if (tid < BB) ids[tid] = x[tid * TT + t];
    __syncthreads();
    for (int r = 0; r < BB; ++r)
        sh[r * (EDIM + 1) + tid] = embed[ids[r] * EDIM + tid];
    __syncthreads();
    for (int i = tid; i < NPAN * EDIM * 8; i += 256) {   // coalesced writes
        int p = i >> 11, k = (i >> 3) & (EDIM - 1), bo = i & 7;
        xe[(size_t)t * (NPAN * EDIM * 8) + i] = sh[(p * 8 + bo) * (EDIM + 1) + k];
    }
}

// ------------------------------------------------------------- reservoir ----
__global__ __launch_bounds__(256, 2) void reservoir_kernel(
    const float* __restrict__ Win0, const float* __restrict__ WinR,
    const float* __restrict__ Rst,  const float* __restrict__ xe,
    float* __restrict__ S, float* __restrict__ Fin, unsigned* __restrict__ cnt)
{
    __shared__ float Wlds[2048 * JW];       // 64 KB, row k = 8 floats (j0..j0+7)
    const int tid   = threadIdx.x;
    const int blk   = blockIdx.x;
    const int layer = blk >> 7;
    const int j0    = (blk & 127) * JW;
    const int Kin   = (layer == 0) ? EDIM : RDIM;

    // rows [0,1024) = R_stack col-slice, rows [1024,1024+Kin) = Win col-slice
    for (int idx = tid; idx < (RDIM + Kin) * JW; idx += 256) {
        int k = idx >> 3, j = idx & 7;
        float wv;
        if (k < RDIM) wv = Rst[((size_t)layer * RDIM + k) * RDIM + j0 + j];
        else {
            int k2 = k - RDIM;
            wv = (layer == 0) ? Win0[(size_t)k2 * RDIM + j0 + j]
                              : WinR[((size_t)(layer - 1) * RDIM + k2) * RDIM + j0 + j];
        }
        Wlds[idx] = wv;
    }
    __syncthreads();

    const int w   = tid >> 6;   // wave -> panel (8 batch rows)
    const int lam = tid & 63;
    const int kq  = lam >> 1;   // 32-way k split within wave
    const int bh  = lam & 1;    // which float4 of the 8-wide row

    for (int tick = 0; tick < TT + NL - 1; ++tick) {
        const int t = tick - layer;
        if (t >= 0 && t < TT) {
            const int cur = tick & 1, prv = cur ^ 1;
            const float4* ownp = (const float4*)(S + (((size_t)(prv * NL + layer) * NPAN + w) * RDIM) * 8);

            float acc[4][8];
            #pragma unroll
            for (int i = 0; i < 4; ++i)
                #pragma unroll
                for (int j = 0; j < 8; ++j) acc[i][j] = 0.f;

            // ---- own state @ R_stack rows (plain cached loads, L2-shared) ----
            #pragma unroll 8
            for (int kk = 0; kk < RDIM / 32; ++kk) {
                float4 v = ownp[(size_t)kk * 64 + lam];            // 1KB/wave contiguous
                int k = kk * 32 + kq;
                float4 w0 = *(const float4*)&Wlds[k * 8];
                float4 w1 = *(const float4*)&Wlds[k * 8 + 4];
                const float vv[4] = {v.x, v.y, v.z, v.w};
                const float wr[8] = {w0.x, w0.y, w0.z, w0.w, w1.x, w1.y, w1.z, w1.w};
                #pragma unroll
                for (int i = 0; i < 4; ++i)
                    #pragma unroll
                    for (int j = 0; j < 8; ++j) acc[i][j] += vv[i] * wr[j];
            }
            // ---- layer input @ Win rows ----
            {
                const float4* inp = (layer == 0)
                    ? (const float4*)(xe + ((size_t)t * NPAN + w) * (EDIM * 8))
                    : (const float4*)(S + (((size_t)(prv * NL + layer - 1) * NPAN + w) * RDIM) * 8);
                #pragma unroll 8
                for (int kk = 0; kk < Kin / 32; ++kk) {
                    float4 v = inp[(size_t)kk * 64 + lam];
                    int k = kk * 32 + kq;
                    float4 w0 = *(const float4*)&Wlds[(RDIM + k) * 8];
                    float4 w1 = *(const float4*)&Wlds[(RDIM + k) * 8 + 4];
                    const float vv[4] = {v.x, v.y, v.z, v.w};
                    const float wr[8] = {w0.x, w0.y, w0.z, w0.w, w1.x, w1.y, w1.z, w1.w};
                    #pragma unroll
                    for (int i = 0; i < 4; ++i)
                        #pragma unroll
                        for (int j = 0; j < 8; ++j) acc[i][j] += vv[i] * wr[j];
                }
            }
            // ---- reduce over kq (lane bits 1..5) ----
            #pragma unroll
            for (int m = 2; m <= 32; m <<= 1)
                #pragma unroll
                for (int i = 0; i < 4; ++i)
                    #pragma unroll
                    for (int j = 0; j < 8; ++j)
                        acc[i][j] += __shfl_xor(acc[i][j], m, 64);

            if (kq < 8) {                       // lane kq -> output column j0+kq
                const int j = kq;
                float o0 = tanhf(acc[0][j]), o1 = tanhf(acc[1][j]);
                float o2 = tanhf(acc[2][j]), o3 = tanhf(acc[3][j]);
                // stores stay agent-scope write-through (visible device-wide)
                ull* dst = (ull*)(S + ((((size_t)(cur * NL + layer) * NPAN + w) * RDIM + (j0 + j)) * 8 + bh * 4));
                __hip_atomic_store(dst,     pack2(o0, o1), __ATOMIC_RELAXED, __HIP_MEMORY_SCOPE_AGENT);
                __hip_atomic_store(dst + 1, pack2(o2, o3), __ATOMIC_RELAXED, __HIP_MEMORY_SCOPE_AGENT);
                if (t == TT - 1) {
                    int jj = layer * RDIM + j0 + j;
                    int b0 = w * 8 + bh * 4;
                    Fin[(size_t)(b0 + 0) * HDIM + jj] = o0;
                    Fin[(size_t)(b0 + 1) * HDIM + jj] = o1;
                    Fin[(size_t)(b0 + 2) * HDIM + jj] = o2;
                    Fin[(size_t)(b0 + 3) * HDIM + jj] = o3;
                }
            }
        }
        // ---- grid barrier: RELEASE arrive, RELAXED poll, ONE acquire fence ----
        __syncthreads();                          // drains every wave's stores
        if (tid == 0)
            __hip_atomic_fetch_add(&cnt[(blk & 15) * CSTRIDE], 1u,
                                   __ATOMIC_RELEASE, __HIP_MEMORY_SCOPE_AGENT);
        if (tid < 64) {                           // wave 0 polls 16 counters
            const unsigned want = (unsigned)(tick + 1) * (unsigned)NBLK;
            int guard = 0;
            for (;;) {
                unsigned v = __hip_atomic_load(&cnt[(lam & 15) * CSTRIDE],
                                               __ATOMIC_RELAXED, __HIP_MEMORY_SCOPE_AGENT);
                #pragma unroll
                for (int m = 1; m <= 8; m <<= 1) v += __shfl_xor(v, m, 64);
                if (v >= want) break;
                __builtin_amdgcn_s_sleep(1);
                if (++guard > (1 << 14)) break;   // safety valve: no GPU hang
            }
            // make all tick-(tau) stores visible to this block's plain loads:
            // single buffer_inv (L1 + XCD-L2 stale-line shootdown)
            __builtin_amdgcn_fence(__ATOMIC_ACQUIRE, "agent");
        }
        __syncthreads();
    }
}

// ------------------------------------------------------------- layernorm ----
__global__ void ln_kernel(const float* __restrict__ Fin,
                          const float* __restrict__ gamma,
                          const float* __restrict__ beta,
                          float* __restrict__ out)
{
    const int r = blockIdx.x, tid = threadIdx.x;
    const float* row = Fin + (size_t)r * HDIM;
    float s = 0.f, s2 = 0.f;
    for (int i = tid; i < HDIM; i += 256) { float v = row[i]; s += v; s2 += v * v; }
    for (int off = 32; off; off >>= 1) {
        s  += __shfl_down(s,  off, 64);
        s2 += __shfl_down(s2, off, 64);
    }
    __shared__ float rs[4], rs2[4];
    __shared__ float mu_s, rstd_s;
    if ((tid & 63) == 0) { rs[tid >> 6] = s; rs2[tid >> 6] = s2; }
    __syncthreads();
    if (tid == 0) {
        float S1 = rs[0] + rs[1] + rs[2] + rs[3];
        float S2 = rs2[0] + rs2[1] + rs2[2] + rs2[3];
        float mu = S1 / (float)HDIM;
        float var = S2 / (float)HDIM - mu * mu;
        mu_s = mu; rstd_s = rsqrtf(var + 1e-5f);
    }
    __syncthreads();
    float mu = mu_s, rstd = rstd_s;
    for (int i = tid; i < HDIM; i += 256)
        out[(size_t)r * HDIM + i] = (row[i] - mu) * rstd * gamma[i] + beta[i];
}

// ----------------------------------------------------------------- launch ---
extern "C" void kernel_launch(void* const* d_in, const int* in_sizes, int n_in,
                              void* d_out, int out_size, void* d_ws, size_t ws_size,
                              hipStream_t stream)
{
    const int*   x     = (const int*)d_in[0];
    const float* embed = (const float*)d_in[1];
    const float* Win0  = (const float*)d_in[2];
    const float* WinR  = (const float*)d_in[3];
    const float* Rst   = (const float*)d_in[4];
    const float* gamma = (const float*)d_in[5];
    const float* beta  = (const float*)d_in[6];
    float* out = (float*)d_out;

    char* ws = (char*)d_ws;
    unsigned* cnt = (unsigned*)ws;                                   // 2KB + pad
    float* S   = (float*)(ws + 8192);                                // 1MB
    float* Fin = (float*)(ws + 8192 + (size_t)S_ELEMS * 4);          // 0.5MB
    float* xe  = (float*)(ws + 8192 + (size_t)(S_ELEMS + FIN_ELEMS) * 4); // 16.8MB

    hipMemsetAsync(ws, 0, 8192 + (size_t)S_ELEMS * 4, stream);       // cnt + states
    gather_kernel   <<<TT,   256, 0, stream>>>(x, embed, xe);
    reservoir_kernel<<<NBLK, 256, 0, stream>>>(Win0, WinR, Rst, xe, S, Fin, cnt);
    ln_kernel       <<<BB,   256, 0, stream>>>(Fin, gamma, beta, out);
}

// Round 4
// 10838.564 us; speedup vs baseline: 1.2138x; 1.2138x over previous
//
#include <hip/hip_runtime.h>
#include <math.h>

// Deep ESN, fp32, persistent wavefront-pipelined kernel, round 4.
// vs R2/R3: (a) state loads are plain cached float4 (L2-dedup across the
// XCD) with exactly ONE agent-acquire fence (buffer_inv sc1) per XCD per
// tick, run by an elected leader BEFORE any block on that XCD reads
// (R3 failed because 512 per-block fences nuked L2 mid-read). Non-leaders
// do an L1-only buffer_inv; state buffers rotate 4-deep as an L1 hedge.
// (b) weight LDS traffic halved: 1 ds_read_b128/lane/iter + DPP lane^1
// exchange for the other half-row; reduction stage-2 via DPP.

#define TT    512
#define RDIM  1024
#define EDIM  256
#define NL    4
#define BB    32
#define NBLK  512          // 128 blocks per layer
#define JW    8            // output columns per block
#define HDIM  (RDIM * NL)  // 4096
#define NPAN  4            // 4 panels of 8 batch rows
#define CSTRIDE 32         // dwords between flag words (128B lines)

#define FIN_ELEMS (BB * HDIM)
#define XE_ELEMS  ((size_t)TT * EDIM * BB)
#define S_ELEMS_P ((size_t)NL * NPAN * RDIM * 8)   // one parity = 128K floats

typedef unsigned long long ull;

__device__ __forceinline__ ull pack2(float a, float b) {
    union { float f[2]; ull u; } c; c.f[0] = a; c.f[1] = b; return c.u;
}
__device__ __forceinline__ float dpp_xor1(float x) {   // lane ^ 1
    return __int_as_float(__builtin_amdgcn_mov_dpp(__float_as_int(x), 0xB1, 0xF, 0xF, true));
}
__device__ __forceinline__ float dpp_xor2(float x) {   // lane ^ 2
    return __int_as_float(__builtin_amdgcn_mov_dpp(__float_as_int(x), 0x4E, 0xF, 0xF, true));
}

// ---------------------------------------------------------------- gather ----
// xe[t][panel][k][8b] : panel layout matching reservoir reads
__global__ void gather_kernel(const int* __restrict__ x,
                              const float* __restrict__ embed,
                              float* __restrict__ xe)
{
    __shared__ int   ids[BB];
    __shared__ float sh[BB * (EDIM + 1)];
    const int t = blockIdx.x, tid = threadIdx.x;
    if (tid < BB) ids[tid] = x[tid * TT + t];
    __syncthreads();
    for (int r = 0; r < BB; ++r)
        sh[r * (EDIM + 1) + tid] = embed[ids[r] * EDIM + tid];
    __syncthreads();
    for (int i = tid; i < NPAN * EDIM * 8; i += 256) {
        int p = i >> 11, k = (i >> 3) & (EDIM - 1), bo = i & 7;
        xe[(size_t)t * (NPAN * EDIM * 8) + i] = sh[(p * 8 + bo) * (EDIM + 1) + k];
    }
}

// ------------------------------------------------------------- reservoir ----
__global__ __launch_bounds__(256, 2) void reservoir_kernel(
    const float* __restrict__ Win0, const float* __restrict__ WinR,
    const float* __restrict__ Rst,  const float* __restrict__ xe,
    float* __restrict__ S, float* __restrict__ Fin,
    unsigned* cnt, unsigned* claimv, unsigned* donev, int pmask)
{
    __shared__ float Wlds[2048 * JW];       // 64 KB, row k = 8 floats (j0..j0+7)
    const int tid   = threadIdx.x;
    const int blk   = blockIdx.x;
    const int layer = blk >> 7;
    const int j0    = (blk & 127) * JW;
    const int Kin   = (layer == 0) ? EDIM : RDIM;

    for (int idx = tid; idx < (RDIM + Kin) * JW; idx += 256) {
        int k = idx >> 3, j = idx & 7;
        float wv;
        if (k < RDIM) wv = Rst[((size_t)layer * RDIM + k) * RDIM + j0 + j];
        else {
            int k2 = k - RDIM;
            wv = (layer == 0) ? Win0[(size_t)k2 * RDIM + j0 + j]
                              : WinR[((size_t)(layer - 1) * RDIM + k2) * RDIM + j0 + j];
        }
        Wlds[idx] = wv;
    }
    __syncthreads();

    const int w   = tid >> 6;   // wave -> panel (8 batch rows)
    const int lam = tid & 63;
    const int kq  = lam >> 1;   // 32-way k split within wave
    const int bh  = lam & 1;    // which float4 of the 8-wide batch row
    const int bh4 = bh * 4;

    unsigned xcc;
    asm volatile("s_getreg_b32 %0, hwreg(HW_REG_XCC_ID)" : "=s"(xcc));
    xcc &= 7u;

    for (int tick = 0; tick < TT + NL - 1; ++tick) {
        const int t = tick - layer;
        if (t >= 0 && t < TT) {
            const int cur = tick & pmask, prv = (tick - 1) & pmask;
            const float4* ownp = (const float4*)(S + (((size_t)(prv * NL + layer)) * NPAN + w) * RDIM * 8);
            const float4* inpp = (layer == 0)
                ? (const float4*)(xe + ((size_t)t * NPAN + w) * (EDIM * 8))
                : (const float4*)(S + (((size_t)(prv * NL + layer - 1)) * NPAN + w) * RDIM * 8);

            float acc[4][8];
            #pragma unroll
            for (int i = 0; i < 4; ++i)
                #pragma unroll
                for (int j = 0; j < 8; ++j) acc[i][j] = 0.f;

            // ---- own state @ R_stack ----
            #pragma unroll 8
            for (int kk = 0; kk < RDIM / 32; ++kk) {
                float4 v  = ownp[(size_t)kk * 64 + lam];              // 1KB/wave
                float4 wo = *(const float4*)&Wlds[(kk * 32 + kq) * 8 + bh4];
                float wr[8];
                wr[0] = wo.x; wr[1] = wo.y; wr[2] = wo.z; wr[3] = wo.w;
                wr[4] = dpp_xor1(wo.x); wr[5] = dpp_xor1(wo.y);
                wr[6] = dpp_xor1(wo.z); wr[7] = dpp_xor1(wo.w);
                const float vv[4] = {v.x, v.y, v.z, v.w};
                #pragma unroll
                for (int i = 0; i < 4; ++i)
                    #pragma unroll
                    for (int j = 0; j < 8; ++j) acc[i][j] += vv[i] * wr[j];
            }
            // ---- layer input @ Win ----
            #pragma unroll 8
            for (int kk = 0; kk < Kin / 32; ++kk) {
                float4 v  = inpp[(size_t)kk * 64 + lam];
                float4 wo = *(const float4*)&Wlds[(RDIM + kk * 32 + kq) * 8 + bh4];
                float wr[8];
                wr[0] = wo.x; wr[1] = wo.y; wr[2] = wo.z; wr[3] = wo.w;
                wr[4] = dpp_xor1(wo.x); wr[5] = dpp_xor1(wo.y);
                wr[6] = dpp_xor1(wo.z); wr[7] = dpp_xor1(wo.w);
                const float vv[4] = {v.x, v.y, v.z, v.w};
                #pragma unroll
                for (int i = 0; i < 4; ++i)
                    #pragma unroll
                    for (int j = 0; j < 8; ++j) acc[i][j] += vv[i] * wr[j];
            }
            // ---- reduce over kq: xor2 via DPP, then 4/8/16/32 shuffles ----
            #pragma unroll
            for (int i = 0; i < 4; ++i)
                #pragma unroll
                for (int j = 0; j < 8; ++j) acc[i][j] += dpp_xor2(acc[i][j]);
            #pragma unroll
            for (int m = 4; m <= 32; m <<= 1)
                #pragma unroll
                for (int i = 0; i < 4; ++i)
                    #pragma unroll
                    for (int j = 0; j < 8; ++j)
                        acc[i][j] += __shfl_xor(acc[i][j], m, 64);

            if (kq < 8) {                       // lane kq -> output column j0+kq
                const int j = kq ^ bh4;         // odd lanes' acc cols are ^4-permuted
                float o0 = tanhf(acc[0][j]), o1 = tanhf(acc[1][j]);
                float o2 = tanhf(acc[2][j]), o3 = tanhf(acc[3][j]);
                ull* dst = (ull*)(S + ((((size_t)(cur * NL + layer)) * NPAN + w) * RDIM + (j0 + kq)) * 8 + bh4);
                __hip_atomic_store(dst,     pack2(o0, o1), __ATOMIC_RELAXED, __HIP_MEMORY_SCOPE_AGENT);
                __hip_atomic_store(dst + 1, pack2(o2, o3), __ATOMIC_RELAXED, __HIP_MEMORY_SCOPE_AGENT);
                if (t == TT - 1) {
                    int jj = layer * RDIM + j0 + kq;
                    int b0 = w * 8 + bh4;
                    Fin[(size_t)(b0 + 0) * HDIM + jj] = o0;
                    Fin[(size_t)(b0 + 1) * HDIM + jj] = o1;
                    Fin[(size_t)(b0 + 2) * HDIM + jj] = o2;
                    Fin[(size_t)(b0 + 3) * HDIM + jj] = o3;
                }
            }
        }
        // ---- grid barrier + per-XCD single L2 invalidate ----
        __syncthreads();                          // drains every wave's stores
        if (tid == 0)
            __hip_atomic_fetch_add(&cnt[(blk & 15) * CSTRIDE], 1u,
                                   __ATOMIC_RELAXED, __HIP_MEMORY_SCOPE_AGENT);
        if (tid < 64) {
            const unsigned want = (unsigned)(tick + 1) * (unsigned)NBLK;
            int guard = 0;
            for (;;) {
                unsigned v = __hip_atomic_load(&cnt[(lam & 15) * CSTRIDE],
                                               __ATOMIC_RELAXED, __HIP_MEMORY_SCOPE_AGENT);
                #pragma unroll
                for (int m = 1; m <= 8; m <<= 1) v += __shfl_xor(v, m, 64);
                if (v >= want) break;
                __builtin_amdgcn_s_sleep(1);
                if (++guard > (1 << 14)) break;   // safety valve
            }
            // elect one leader per XCD; leader invs L2 BEFORE anyone reads
            const unsigned wantx = (unsigned)(tick + 1);
            int lead = 0;
            if (lam == 0) {
                unsigned old = __hip_atomic_fetch_max(&claimv[xcc * CSTRIDE], wantx,
                                                      __ATOMIC_RELAXED, __HIP_MEMORY_SCOPE_AGENT);
                lead = (old < wantx) ? 1 : 0;
            }
            lead = __shfl(lead, 0, 64);
            if (lead) {
                __builtin_amdgcn_fence(__ATOMIC_ACQUIRE, "agent"); // waitcnt + buffer_inv sc1
                asm volatile("s_waitcnt vmcnt(0)" ::: "memory");
                if (lam == 0)
                    __hip_atomic_store(&donev[xcc * CSTRIDE], wantx,
                                       __ATOMIC_RELAXED, __HIP_MEMORY_SCOPE_AGENT);
            } else {
                if (lam == 0) {
                    int g2 = 0;
                    while (__hip_atomic_load(&donev[xcc * CSTRIDE],
                                             __ATOMIC_RELAXED, __HIP_MEMORY_SCOPE_AGENT) < wantx) {
                        if (++g2 > (1 << 18)) break;
                    }
                }
                asm volatile("buffer_inv" ::: "memory");           // own-CU L1 only
            }
        }
        __syncthreads();
    }
}

// ------------------------------------------------------------- layernorm ----
__global__ void ln_kernel(const float* __restrict__ Fin,
                          const float* __restrict__ gamma,
                          const float* __restrict__ beta,
                          float* __restrict__ out)
{
    const int r = blockIdx.x, tid = threadIdx.x;
    const float* row = Fin + (size_t)r * HDIM;
    float s = 0.f, s2 = 0.f;
    for (int i = tid; i < HDIM; i += 256) { float v = row[i]; s += v; s2 += v * v; }
    for (int off = 32; off; off >>= 1) {
        s  += __shfl_down(s,  off, 64);
        s2 += __shfl_down(s2, off, 64);
    }
    __shared__ float rs[4], rs2[4];
    __shared__ float mu_s, rstd_s;
    if ((tid & 63) == 0) { rs[tid >> 6] = s; rs2[tid >> 6] = s2; }
    __syncthreads();
    if (tid == 0) {
        float S1 = rs[0] + rs[1] + rs[2] + rs[3];
        float S2 = rs2[0] + rs2[1] + rs2[2] + rs2[3];
        float mu = S1 / (float)HDIM;
        float var = S2 / (float)HDIM - mu * mu;
        mu_s = mu; rstd_s = rsqrtf(var + 1e-5f);
    }
    __syncthreads();
    float mu = mu_s, rstd = rstd_s;
    for (int i = tid; i < HDIM; i += 256)
        out[(size_t)r * HDIM + i] = (row[i] - mu) * rstd * gamma[i] + beta[i];
}

// ----------------------------------------------------------------- launch ---
extern "C" void kernel_launch(void* const* d_in, const int* in_sizes, int n_in,
                              void* d_out, int out_size, void* d_ws, size_t ws_size,
                              hipStream_t stream)
{
    const int*   x     = (const int*)d_in[0];
    const float* embed = (const float*)d_in[1];
    const float* Win0  = (const float*)d_in[2];
    const float* WinR  = (const float*)d_in[3];
    const float* Rst   = (const float*)d_in[4];
    const float* gamma = (const float*)d_in[5];
    const float* beta  = (const float*)d_in[6];
    float* out = (float*)d_out;

    char* ws = (char*)d_ws;
    unsigned* cnt    = (unsigned*)ws;                 // 16 lines
    unsigned* claimv = cnt    + 16 * CSTRIDE;         // 8 lines
    unsigned* donev  = claimv + 8  * CSTRIDE;         // 8 lines

    // 4-deep state rotation if workspace allows, else 2-deep
    size_t need4 = 8192 + (4 * S_ELEMS_P + FIN_ELEMS + XE_ELEMS) * 4;
    int   pmask  = (ws_size >= need4) ? 3 : 1;
    size_t s_el  = (size_t)(pmask + 1) * S_ELEMS_P;

    float* S   = (float*)(ws + 8192);
    float* Fin = S + s_el;
    float* xe  = Fin + FIN_ELEMS;

    hipMemsetAsync(ws, 0, 8192 + s_el * 4, stream);   // flags + states
    gather_kernel   <<<TT,   256, 0, stream>>>(x, embed, xe);
    reservoir_kernel<<<NBLK, 256, 0, stream>>>(Win0, WinR, Rst, xe, S, Fin,
                                               cnt, claimv, donev, pmask);
    ln_kernel       <<<BB,   256, 0, stream>>>(Fin, gamma, beta, out);
}